// Round 7
// baseline (1413.643 us; speedup 1.0000x reference)
//
#include <hip/hip_runtime.h>

#define B_ 256
#define T_ 512
#define I_ 64
#define H_ 512
#define O_ 16

typedef _Float16 half8 __attribute__((ext_vector_type(8)));
typedef _Float16 half4 __attribute__((ext_vector_type(4)));
typedef float    f32x4 __attribute__((ext_vector_type(4)));

#define MFMA16(a, b, c) __builtin_amdgcn_mfma_f32_16x16x32_f16((a), (b), (c), 0, 0, 0)

__device__ inline half8 cvt_h8(f32x4 a, f32x4 b) {
  half8 v;
  v[0] = (_Float16)a[0]; v[1] = (_Float16)a[1]; v[2] = (_Float16)a[2]; v[3] = (_Float16)a[3];
  v[4] = (_Float16)b[0]; v[5] = (_Float16)b[1]; v[6] = (_Float16)b[2]; v[7] = (_Float16)b[3];
  return v;
}

// ---------------- prepass: xp = W_ih @ x_t^T + b  (D-layout: col=batch, row=j) ----
// Stored f16 in EXACT consumer order: half-index
//   ((t*16+g)*256 + w_c*64 + lane)*32 + ln*4 + i
// Stores aggregated to half8 (b128) for write-combining (was 128 scalar b64s).
__global__ __launch_bounds__(256, 2)
void xp_prepass(const float* __restrict__ x, const float* __restrict__ W_ih,
                const float* __restrict__ b_ih, const float* __restrict__ b_hh,
                _Float16* __restrict__ xp) {
  const int tid = threadIdx.x, L = tid & 63, w = tid >> 6;
  const int n = L & 15, kq = (L >> 4) & 3;
  const int g = blockIdx.x & 15, tc = blockIdx.x >> 4;   // 512 blocks = 16 g x 32 tc

  __shared__ __attribute__((aligned(16))) _Float16 wlih[32 * 2 * 64 * 8]; // 64 KB A-frags
  __shared__ float biasl[512];
  const half8* wlih8 = (const half8*)wlih;

  // stage W_ih as A-fragments: slot s = (jt*2+c)*64 + L'
  #pragma unroll
  for (int u = 0; u < 16; ++u) {
    const int s = tid + u * 256;                 // [0,4096)
    const int jt = s >> 7, c = (s >> 6) & 1, Lp = s & 63;
    const int jl = Lp & 15, kq2 = Lp >> 4;
    const float* p = W_ih + (jt * 16 + jl) * I_ + c * 32 + kq2 * 8;
    ((half8*)wlih)[s] = cvt_h8(*(const f32x4*)(p), *(const f32x4*)(p + 4));
  }
  #pragma unroll
  for (int u = 0; u < 2; ++u) {
    const int idx = tid + u * 256;
    biasl[idx] = b_ih[idx] + b_hh[idx];
  }
  __syncthreads();

  // x B-fragments for this wave's 4 timesteps
  half8 xb[4][2];
  #pragma unroll
  for (int rr = 0; rr < 4; ++rr) {
    const int t = tc * 16 + w * 4 + rr;
    const float* p = x + ((size_t)(g * 16 + n) * T_ + t) * I_ + kq * 8;
    xb[rr][0] = cvt_h8(*(const f32x4*)(p),      *(const f32x4*)(p + 4));
    xb[rr][1] = cvt_h8(*(const f32x4*)(p + 32), *(const f32x4*)(p + 36));
  }

  #pragma unroll 1
  for (int hi = 0; hi < 4; ++hi) {             // consumer wave index = hi
    half8 o[4][4];                             // [rr][quarter of 32-half slot]
    #pragma unroll
    for (int jt2 = 0; jt2 < 8; ++jt2) {
      const int jt = hi * 8 + jt2;             // ln = jt2
      const half8 a0 = wlih8[(jt * 2 + 0) * 64 + L];
      const half8 a1 = wlih8[(jt * 2 + 1) * 64 + L];
      const f32x4 bv = *(const f32x4*)&biasl[jt * 16 + 4 * kq];
      #pragma unroll
      for (int rr = 0; rr < 4; ++rr) {
        f32x4 acc; acc[0] = 0.f; acc[1] = 0.f; acc[2] = 0.f; acc[3] = 0.f;
        acc = MFMA16(a0, xb[rr][0], acc);
        acc = MFMA16(a1, xb[rr][1], acc);
        #pragma unroll
        for (int i = 0; i < 4; ++i)
          o[rr][jt2 >> 1][(jt2 & 1) * 4 + i] = (_Float16)(acc[i] + bv[i]);
      }
    }
    #pragma unroll
    for (int rr = 0; rr < 4; ++rr) {
      const int t = tc * 16 + w * 4 + rr;
      _Float16* dst = xp + ((size_t)(t * 16 + g) * 256 + hi * 64 + L) * 32;
      #pragma unroll
      for (int qq = 0; qq < 4; ++qq) *(half8*)(dst + qq * 8) = o[rr][qq];
    }
  }
}

// ---------------- main persistent RNN ----------------
// 16 blocks x 256 threads (4 waves, 1/SIMD, 512-reg unified budget). Wave w
// owns j in [128w,128w+128). kc visit order is ROTATED per wave: seq position
// ii -> kc = (4w+ii)&15, so a wave starts on the slice it wrote itself.
// Weight storage by ii: 0..7 AGPR (class-pinned), 8..12 arch VGPR, 13..15 LDS.
// B-frags: 3-deep explicit prefetch (bq[3]); first 3 of the NEXT step are read
// pre-barrier from the wave's own epilogue writes (same-wave DS order).
// LDS weights: 2-deep rolling prefetch (static data). ONE barrier per step.
__global__ __launch_bounds__(256, 1)
void rnn_persist(const float* __restrict__ h0, const float* __restrict__ W_hh,
                 const float* __restrict__ W_fc, const float* __restrict__ b_fc,
                 float* __restrict__ out, const _Float16* __restrict__ xp) {
  const int tid = threadIdx.x;
  const int L   = tid & 63;
  const int w   = tid >> 6;        // wave 0..3
  const int w4  = w * 4;
  const int n   = L & 15;          // batch col (B/D) or j-local (A)
  const int kq  = (L >> 4) & 3;
  const int g   = blockIdx.x;      // batches [16g, 16g+16)

  __shared__ __attribute__((aligned(16))) _Float16 hb[2 * 16 * 64 * 8];   // 32 KB
  __shared__ __attribute__((aligned(16))) _Float16 wlds[4 * 24 * 64 * 8]; // 96 KB
  half8* hb8 = (half8*)hb;
  const half8* wl8 = (const half8*)wlds;
  half8* wlw = (half8*)wlds;

  // ---- resident W_hh A-fragments (lane: j = w*128 + ln*16 + n, k-run kq*8) ----
  half8 whA[64];   // seq ii 0..7   -> 256 AGPR (class-pinned)
  half8 whV[40];   // seq ii 8..12  -> 160 arch VGPR
  #pragma unroll
  for (int ln = 0; ln < 8; ++ln) {
    const int j = w * 128 + ln * 16 + n;
    #pragma unroll
    for (int ii = 0; ii < 8; ++ii) {
      const int kc = (w4 + ii) & 15;
      const f32x4* p = (const f32x4*)(W_hh + j * H_ + kc * 32 + kq * 8);
      whA[ln * 8 + ii] = cvt_h8(p[0], p[1]);
    }
    #pragma unroll
    for (int ii = 8; ii < 13; ++ii) {
      const int kc = (w4 + ii) & 15;
      const f32x4* p = (const f32x4*)(W_hh + j * H_ + kc * 32 + kq * 8);
      whV[ln * 5 + (ii - 8)] = cvt_h8(p[0], p[1]);
    }
    #pragma unroll
    for (int s = 0; s < 3; ++s) {              // seq ii = 13+s
      const int kc = (w4 + 13 + s) & 15;
      const f32x4* p = (const f32x4*)(W_hh + j * H_ + kc * 32 + kq * 8);
      wlw[(w * 24 + s * 8 + ln) * 64 + L] = cvt_h8(p[0], p[1]);
    }
  }
  // One-time AGPR class pin (MFMAs stay builtins; hazards compiler-handled).
  #pragma unroll
  for (int i2 = 0; i2 < 64; ++i2) asm volatile("" : "+a"(whA[i2]));

  // ---- h(0) into B-layout buffer 0: half8 slot S = k8*16 + nb ----
  #pragma unroll
  for (int u = 0; u < 4; ++u) {
    const int S = tid + u * 256;                 // [0,1024)
    const int k8 = S >> 4, nb = S & 15;
    const float* p = h0 + (g * 16 + nb) * H_ + k8 * 8;
    hb8[S] = cvt_h8(*(const f32x4*)(p), *(const f32x4*)(p + 4));
  }
  __syncthreads();

  // prologue: B-frag prefetch for seq 0..2 (kc = 4w..4w+2) from buffer 0
  half8 bq[3];
  #pragma unroll
  for (int d = 0; d < 3; ++d) bq[d] = hb8[(w4 + d) * 64 + L];

  // xp for t=0 (4 x half8 per thread)
  half8 xq[4];
  {
    const half8* p0 = (const half8*)(xp + ((size_t)(0 * 16 + g) * 256 + tid) * 32);
    #pragma unroll
    for (int e = 0; e < 4; ++e) xq[e] = p0[e];
  }

  #pragma unroll 1
  for (int t = 0; t < T_; ++t) {
    const half8* hbr = hb8 + (t & 1) * 1024;
    half8* hbw = hb8 + ((t + 1) & 1) * 1024;

    // acc init from xp: acc[ln][i] for row j = w*128 + ln*16 + 4kq + i, col n
    f32x4 acc[8];
    #pragma unroll
    for (int ln = 0; ln < 8; ++ln)
      #pragma unroll
      for (int i = 0; i < 4; ++i)
        acc[ln][i] = (float)(xq[ln >> 1][(ln & 1) * 4 + i]);

    // reload xq for t+1 (in flight across the MFMA wall; drained by barrier)
    {
      const int tn = (t + 1) & (T_ - 1);
      const half8* pn = (const half8*)(xp + ((size_t)(tn * 16 + g) * 256 + tid) * 32);
      #pragma unroll
      for (int e = 0; e < 4; ++e) xq[e] = pn[e];
    }

    // LDS-weight rolling prefetch warm-up (static data: any time is legal)
    half8 wp[2];
    wp[0] = wl8[(w * 24 + 0) * 64 + L];
    wp[1] = wl8[(w * 24 + 1) * 64 + L];

    // MFMA wall over 16 seq groups, kc = (4w+ii)&15
    #pragma unroll
    for (int ii = 0; ii < 16; ++ii) {
      const half8 bc = bq[ii % 3];
      if (ii < 13)   // prefetch B for seq ii+3
        bq[ii % 3] = hbr[(((w4 + ii + 3) & 15)) * 64 + L];
      if (ii < 8) {
        #pragma unroll
        for (int ln = 0; ln < 8; ++ln)
          acc[ln] = MFMA16(whA[ln * 8 + ii], bc, acc[ln]);
      } else if (ii < 13) {
        #pragma unroll
        for (int ln = 0; ln < 8; ++ln)
          acc[ln] = MFMA16(whV[ln * 5 + (ii - 8)], bc, acc[ln]);
      } else {
        #pragma unroll
        for (int ln = 0; ln < 8; ++ln) {
          const int u = (ii - 13) * 8 + ln;    // 0..23
          const half8 wc = wp[u & 1];
          if (u + 2 < 24) wp[u & 1] = wl8[(w * 24 + u + 2) * 64 + L];
          acc[ln] = MFMA16(wc, bc, acc[ln]);
        }
      }
    }

    // epilogue: relu -> b64 writes into next buffer (own kc range [4w,4w+4))
    // thread covers j = w*128 + ln*16 + 4kq + i, col n:
    // slot S = (w*16 + ln*2 + (kq>>1))*16 + n, half-offset 4*(kq&1)
    #pragma unroll
    for (int ln = 0; ln < 8; ++ln) {
      half4 hv;
      #pragma unroll
      for (int i = 0; i < 4; ++i) hv[i] = (_Float16)fmaxf(acc[ln][i], 0.f);
      const int S = (w * 16 + ln * 2 + (kq >> 1)) * 16 + n;
      *(half4*)((_Float16*)hbw + S * 8 + 4 * (kq & 1)) = hv;
    }

    // pre-barrier self-prefetch of next step's first 3 B-frags (own writes;
    // same-wave DS ordering guarantees visibility)
    #pragma unroll
    for (int d = 0; d < 3; ++d) bq[d] = hbw[(w4 + d) * 64 + L];

    __syncthreads();   // one barrier per step
  }

  // ---- output 1: h_last (1,B,H) fp32 at out+4096 (final h in buffer 0) ----
  const half8* hf = hb8;   // buffer 0 (T even)
  #pragma unroll
  for (int u = 0; u < 4; ++u) {
    const int k8 = (tid >> 4) * 4 + u, nb = tid & 15;
    const half8 v = hf[k8 * 16 + nb];
    float* dst = out + 4096 + (g * 16 + nb) * H_ + k8 * 8;
    #pragma unroll
    for (int e = 0; e < 8; ++e) dst[e] = (float)v[e];
  }
  // ---- output 0: FC (reuse wlds as fp32 [16][513]) ----
  __syncthreads();
  float* wfcf = (float*)wlds;
  #pragma unroll
  for (int u = 0; u < 32; ++u) {
    const int idx = tid + u * 256;
    wfcf[(idx >> 9) * 513 + (idx & 511)] = W_fc[idx];
  }
  __syncthreads();
  {
    const int bl = tid >> 4, o = tid & 15;
    float s = 0.f;
    #pragma unroll 8
    for (int k8 = 0; k8 < 64; ++k8) {
      const half8 v = hf[k8 * 16 + bl];
      #pragma unroll
      for (int e = 0; e < 8; ++e) s += (float)v[e] * wfcf[o * 513 + k8 * 8 + e];
    }
    out[(g * 16 + bl) * 16 + o] = s + b_fc[o];
  }
}

extern "C" void kernel_launch(void* const* d_in, const int* in_sizes, int n_in,
                              void* d_out, int out_size, void* d_ws, size_t ws_size,
                              hipStream_t stream) {
  const float* x    = (const float*)d_in[0];
  const float* h0   = (const float*)d_in[1];
  const float* W_ih = (const float*)d_in[2];
  const float* W_hh = (const float*)d_in[3];
  const float* b_ih = (const float*)d_in[4];
  const float* b_hh = (const float*)d_in[5];
  const float* W_fc = (const float*)d_in[6];
  const float* b_fc = (const float*)d_in[7];
  float* out = (float*)d_out;

  _Float16* xp = (_Float16*)d_ws;   // 134 MB f16 workspace

  xp_prepass<<<dim3(512), dim3(256), 0, stream>>>(x, W_ih, b_ih, b_hh, xp);
  rnn_persist<<<dim3(16), dim3(256), 0, stream>>>(h0, W_hh, W_fc, b_fc, out, xp);
}

// Round 8
// 891.992 us; speedup vs baseline: 1.5848x; 1.5848x over previous
//
#include <hip/hip_runtime.h>

#define B_ 256
#define T_ 512
#define I_ 64
#define H_ 512
#define O_ 16

typedef _Float16 half8 __attribute__((ext_vector_type(8)));
typedef _Float16 half4 __attribute__((ext_vector_type(4)));
typedef float    f32x4 __attribute__((ext_vector_type(4)));

#define MFMA16(a, b, c) __builtin_amdgcn_mfma_f32_16x16x32_f16((a), (b), (c), 0, 0, 0)

__device__ inline half8 cvt_h8(f32x4 a, f32x4 b) {
  half8 v;
  v[0] = (_Float16)a[0]; v[1] = (_Float16)a[1]; v[2] = (_Float16)a[2]; v[3] = (_Float16)a[3];
  v[4] = (_Float16)b[0]; v[5] = (_Float16)b[1]; v[6] = (_Float16)b[2]; v[7] = (_Float16)b[3];
  return v;
}

// ---------------- prepass: xp = W_ih @ x_t^T + b  (D-layout: col=batch, row=j) ----
// Stored f16 in EXACT consumer order for the 512-thread main kernel:
// consumer thread tid_c = w*64 + kq*16 + n covers j = w*64 + ln*16 + 4kq + i
// (ln 0..3), batch = g*16 + n. Half-index = ((t*16+g)*512 + tid_c)*16 + ln*4 + i.
__global__ __launch_bounds__(256, 2)
void xp_prepass(const float* __restrict__ x, const float* __restrict__ W_ih,
                const float* __restrict__ b_ih, const float* __restrict__ b_hh,
                _Float16* __restrict__ xp) {
  const int tid = threadIdx.x, L = tid & 63, w = tid >> 6;
  const int n = L & 15, kq = (L >> 4) & 3;
  const int g = blockIdx.x & 15, tc = blockIdx.x >> 4;   // 512 blocks = 16 g x 32 tc

  __shared__ __attribute__((aligned(16))) _Float16 wlih[32 * 2 * 64 * 8]; // 64 KB A-frags
  __shared__ float biasl[512];
  const half8* wlih8 = (const half8*)wlih;

  // stage W_ih as A-fragments: slot s = (jt*2+c)*64 + L'
  #pragma unroll
  for (int u = 0; u < 16; ++u) {
    const int s = tid + u * 256;                 // [0,4096)
    const int jt = s >> 7, c = (s >> 6) & 1, Lp = s & 63;
    const int jl = Lp & 15, kq2 = Lp >> 4;
    const float* p = W_ih + (jt * 16 + jl) * I_ + c * 32 + kq2 * 8;
    ((half8*)wlih)[s] = cvt_h8(*(const f32x4*)(p), *(const f32x4*)(p + 4));
  }
  #pragma unroll
  for (int u = 0; u < 2; ++u) {
    const int idx = tid + u * 256;
    biasl[idx] = b_ih[idx] + b_hh[idx];
  }
  __syncthreads();

  // x B-fragments for this wave's 4 timesteps
  half8 xb[4][2];
  #pragma unroll
  for (int rr = 0; rr < 4; ++rr) {
    const int t = tc * 16 + w * 4 + rr;
    const float* p = x + ((size_t)(g * 16 + n) * T_ + t) * I_ + kq * 8;
    xb[rr][0] = cvt_h8(*(const f32x4*)(p),      *(const f32x4*)(p + 4));
    xb[rr][1] = cvt_h8(*(const f32x4*)(p + 32), *(const f32x4*)(p + 36));
  }

  #pragma unroll 1
  for (int hi = 0; hi < 8; ++hi) {             // consumer wave index
    half8 o[4][2];                             // [rr][half of 16-half slot]
    #pragma unroll
    for (int jt2 = 0; jt2 < 4; ++jt2) {        // consumer ln
      const int jt = hi * 4 + jt2;
      const half8 a0 = wlih8[(jt * 2 + 0) * 64 + L];
      const half8 a1 = wlih8[(jt * 2 + 1) * 64 + L];
      const f32x4 bv = *(const f32x4*)&biasl[jt * 16 + 4 * kq];
      #pragma unroll
      for (int rr = 0; rr < 4; ++rr) {
        f32x4 acc; acc[0] = 0.f; acc[1] = 0.f; acc[2] = 0.f; acc[3] = 0.f;
        acc = MFMA16(a0, xb[rr][0], acc);
        acc = MFMA16(a1, xb[rr][1], acc);
        #pragma unroll
        for (int i = 0; i < 4; ++i)
          o[rr][jt2 >> 1][(jt2 & 1) * 4 + i] = (_Float16)(acc[i] + bv[i]);
      }
    }
    #pragma unroll
    for (int rr = 0; rr < 4; ++rr) {
      const int t = tc * 16 + w * 4 + rr;
      _Float16* dst = xp + ((size_t)(t * 16 + g) * 512 + hi * 64 + L) * 16;
      *(half8*)(dst)     = o[rr][0];
      *(half8*)(dst + 8) = o[rr][1];
    }
  }
}

// ---------------- main persistent RNN (TLP overlap) ----------------
// 16 blocks x 512 threads (8 waves, 2/SIMD, 256 unified regs/wave). Wave w
// owns j in [64w, 64w+64) (4 ln-tiles). W_hh per wave: kc 0..7 AGPR-pinned
// (128), kc 8..12 arch VGPR (80), kc 13..15 LDS (96 KB). h double-buffered
// in LDS B-frag layout (32 KB). With 2 waves/SIMD the HW co-schedules one
// wave's MFMA wall against the other's LDS reads/epilogue (m114) — no manual
// pipelining. ONE barrier per step.
__global__ __launch_bounds__(512, 2)
void rnn_persist(const float* __restrict__ h0, const float* __restrict__ W_hh,
                 const float* __restrict__ W_fc, const float* __restrict__ b_fc,
                 float* __restrict__ out, const _Float16* __restrict__ xp) {
  const int tid = threadIdx.x;
  const int L   = tid & 63;
  const int w   = tid >> 6;        // wave 0..7
  const int n   = L & 15;          // batch col (B/D) or j-local (A)
  const int kq  = (L >> 4) & 3;
  const int g   = blockIdx.x;      // batches [16g, 16g+16)

  __shared__ __attribute__((aligned(16))) _Float16 hb[2 * 16 * 64 * 8];   // 32 KB
  __shared__ __attribute__((aligned(16))) _Float16 wlds[8 * 12 * 64 * 8]; // 96 KB
  half8* hb8 = (half8*)hb;
  const half8* wl8 = (const half8*)wlds;
  half8* wlw = (half8*)wlds;

  // ---- resident W_hh A-fragments (lane: j = w*64 + ln*16 + n, k-run kq*8) ----
  half8 whA[32];   // kc 0..7  -> 128 AGPR (class-pinned)
  half8 whV[20];   // kc 8..12 -> 80 arch VGPR
  #pragma unroll
  for (int ln = 0; ln < 4; ++ln) {
    const int j = w * 64 + ln * 16 + n;
    #pragma unroll
    for (int kc = 0; kc < 8; ++kc) {
      const f32x4* p = (const f32x4*)(W_hh + j * H_ + kc * 32 + kq * 8);
      whA[ln * 8 + kc] = cvt_h8(p[0], p[1]);
    }
    #pragma unroll
    for (int kc = 0; kc < 5; ++kc) {
      const f32x4* p = (const f32x4*)(W_hh + j * H_ + (8 + kc) * 32 + kq * 8);
      whV[ln * 5 + kc] = cvt_h8(p[0], p[1]);
    }
    #pragma unroll
    for (int s = 0; s < 3; ++s) {              // kc = 13+s
      const f32x4* p = (const f32x4*)(W_hh + j * H_ + (13 + s) * 32 + kq * 8);
      wlw[(w * 12 + s * 4 + ln) * 64 + L] = cvt_h8(p[0], p[1]);
    }
  }
  // One-time AGPR class pin (MFMAs stay builtins; hazards compiler-handled).
  #pragma unroll
  for (int i2 = 0; i2 < 32; ++i2) asm volatile("" : "+a"(whA[i2]));

  // ---- h(0) into B-layout buffer 0: half8 slot S = k8*16 + nb ----
  #pragma unroll
  for (int u = 0; u < 2; ++u) {
    const int S = tid + u * 512;                 // [0,1024)
    const int k8 = S >> 4, nb = S & 15;
    const float* p = h0 + (g * 16 + nb) * H_ + k8 * 8;
    hb8[S] = cvt_h8(*(const f32x4*)(p), *(const f32x4*)(p + 4));
  }
  __syncthreads();

  // xp for t=0 (2 x half8 per thread)
  half8 xq0, xq1;
  {
    const half8* p0 = (const half8*)(xp + ((size_t)(0 * 16 + g) * 512 + tid) * 16);
    xq0 = p0[0]; xq1 = p0[1];
  }

  #pragma unroll 1
  for (int t = 0; t < T_; ++t) {
    const half8* hbr = hb8 + (t & 1) * 1024;
    half8* hbw = hb8 + ((t + 1) & 1) * 1024;

    // acc init from xp: acc[ln][i] for row j = w*64 + ln*16 + 4kq + i, col n
    f32x4 acc[4];
    #pragma unroll
    for (int ln = 0; ln < 4; ++ln)
      #pragma unroll
      for (int i = 0; i < 4; ++i)
        acc[ln][i] = (float)((ln < 2 ? xq0 : xq1)[(ln & 1) * 4 + i]);

    // prefetch xp for t+1 (in flight across the MFMA wall)
    {
      const int tn = (t + 1) & (T_ - 1);
      const half8* pn = (const half8*)(xp + ((size_t)(tn * 16 + g) * 512 + tid) * 16);
      xq0 = pn[0]; xq1 = pn[1];
    }

    // MFMA wall: A = weights, B = h
    #pragma unroll
    for (int kc = 0; kc < 8; ++kc) {
      const half8 b = hbr[kc * 64 + L];
      #pragma unroll
      for (int ln = 0; ln < 4; ++ln) acc[ln] = MFMA16(whA[ln * 8 + kc], b, acc[ln]);
    }
    #pragma unroll
    for (int kc = 0; kc < 5; ++kc) {
      const half8 b = hbr[(8 + kc) * 64 + L];
      #pragma unroll
      for (int ln = 0; ln < 4; ++ln) acc[ln] = MFMA16(whV[ln * 5 + kc], b, acc[ln]);
    }
    #pragma unroll
    for (int s = 0; s < 3; ++s) {
      const half8 b = hbr[(13 + s) * 64 + L];
      #pragma unroll
      for (int ln = 0; ln < 4; ++ln)
        acc[ln] = MFMA16(wl8[(w * 12 + s * 4 + ln) * 64 + L], b, acc[ln]);
    }

    // epilogue: relu -> b64 writes into next buffer.
    // thread covers j = w*64 + ln*16 + 4kq + i, col n:
    // half8 slot S = (w*8 + ln*2 + (kq>>1))*16 + n, half-offset 4*(kq&1)
    #pragma unroll
    for (int ln = 0; ln < 4; ++ln) {
      half4 hv;
      #pragma unroll
      for (int i = 0; i < 4; ++i) hv[i] = (_Float16)fmaxf(acc[ln][i], 0.f);
      const int S = (w * 8 + ln * 2 + (kq >> 1)) * 16 + n;
      *(half4*)((_Float16*)hbw + S * 8 + 4 * (kq & 1)) = hv;
    }
    __syncthreads();   // one barrier per step
  }

  // ---- output 1: h_last (1,B,H) fp32 at out+4096 (final h in buffer 0) ----
  const half8* hf = hb8;   // buffer 0 (T even)
  #pragma unroll
  for (int u = 0; u < 2; ++u) {
    const int ri = tid + u * 512;
    const int k8 = ri >> 4, nb = ri & 15;
    const half8 v = hf[k8 * 16 + nb];
    float* dst = out + 4096 + (g * 16 + nb) * H_ + k8 * 8;
    #pragma unroll
    for (int e = 0; e < 8; ++e) dst[e] = (float)v[e];
  }
  // ---- output 0: FC (reuse wlds as fp32 [16][513]) ----
  __syncthreads();
  float* wfcf = (float*)wlds;
  #pragma unroll
  for (int u = 0; u < 16; ++u) {
    const int idx = tid + u * 512;
    wfcf[(idx >> 9) * 513 + (idx & 511)] = W_fc[idx];
  }
  __syncthreads();
  if (tid < 256) {
    const int bl = tid >> 4, o = tid & 15;
    float s = 0.f;
    #pragma unroll 8
    for (int k8 = 0; k8 < 64; ++k8) {
      const half8 v = hf[k8 * 16 + bl];
      #pragma unroll
      for (int e = 0; e < 8; ++e) s += (float)v[e] * wfcf[o * 513 + k8 * 8 + e];
    }
    out[(g * 16 + bl) * 16 + o] = s + b_fc[o];
  }
}

extern "C" void kernel_launch(void* const* d_in, const int* in_sizes, int n_in,
                              void* d_out, int out_size, void* d_ws, size_t ws_size,
                              hipStream_t stream) {
  const float* x    = (const float*)d_in[0];
  const float* h0   = (const float*)d_in[1];
  const float* W_ih = (const float*)d_in[2];
  const float* W_hh = (const float*)d_in[3];
  const float* b_ih = (const float*)d_in[4];
  const float* b_hh = (const float*)d_in[5];
  const float* W_fc = (const float*)d_in[6];
  const float* b_fc = (const float*)d_in[7];
  float* out = (float*)d_out;

  _Float16* xp = (_Float16*)d_ws;   // 134 MB f16 workspace

  xp_prepass<<<dim3(512), dim3(256), 0, stream>>>(x, W_ih, b_ih, b_hh, xp);
  rnn_persist<<<dim3(16), dim3(512), 0, stream>>>(h0, W_hh, W_fc, b_fc, out, xp);
}